// Round 5
// baseline (188.495 us; speedup 1.0000x reference)
//
#include <hip/hip_runtime.h>
#include <hip/hip_bf16.h>

typedef unsigned short u16;
typedef unsigned int   u32;

typedef __bf16 bf16x8 __attribute__((ext_vector_type(8)));
typedef float  f32x4  __attribute__((ext_vector_type(4)));

__device__ __forceinline__ u16 f2b(float f) {
    __hip_bfloat16 h = __float2bfloat16(f);
    u16 u; __builtin_memcpy(&u, &h, 2); return u;
}
__device__ __forceinline__ float blo(u32 u) { return __uint_as_float(u << 16); }
__device__ __forceinline__ float bhi(u32 u) { return __uint_as_float(u & 0xffff0000u); }

// ---------------------------------------------------------------------------
// prep (unchanged):
//  section B (blocks [0,1152)):    weights -> MFMA B-fragment order
//       BF[(((p*4+g)*4+q)*256 + n)*8 + j] = bf16(w[(p*128+g*32+q*8+j)*256+n])
//  section C (blocks [1152,1200)): zero s0,s2,s3 (12288 floats)
// ---------------------------------------------------------------------------
__global__ void k_prep(const float* __restrict__ wk,
                       u16* __restrict__ BF, float* __restrict__ stats) {
    int bx = blockIdx.x, tid = threadIdx.x;
    if (bx < 1152) {
        int t = bx * 256 + tid;                   // 294912 total, exact
        int j  = t & 7;
        int n  = (t >> 3) & 255;
        int q  = (t >> 11) & 3;
        int kk = (t >> 13) & 3;
        int p  = t >> 15;
        BF[t] = f2b(wk[(p * 128 + kk * 32 + q * 8 + j) * 256 + n]);
    } else {
        stats[(bx - 1152) * 256 + tid] = 0.f;     // 12288 floats
    }
}

// ---------------------------------------------------------------------------
// conv: implicit GEMM. R17.
// Post-mortem chain:
//  R13: allocator squeeze on 64x64 tile -> spill. R15: 4-frag ping-pong =
//  too little cover + LDS conflicts. R16: conflicts fixed, occupancy 36%,
//  STILL 67us > R12's 60us -> occupancy is NOT the limiter. What tracked
//  duration across R12/R15/R16 is B-fragment VMEM traffic (~64 B/cyc/CU
//  L1->reg pipe): R12 2.3MB/CU (~15us), R16 4.6MB/CU (~30us). MFMA floor
//  is 18.6us/CU. Fix = arithmetic intensity per B-byte, not TLP.
// R17: block = 2 image rows: M=128, N=256, K=1152. 4 waves (256 thr),
//  wave tile 128x64 (mi=8: mi>>2 = image row, mi&3 = w-block; wid = wc).
//  Grid 512 = 16 batches x 32 row-pairs -> EXACTLY 2 blocks/CU, whole
//  grid resident, B read once per block:
//   - B-VMEM/CU = 2 x 576KB = 1.15MB (~7.9us)  [R16: 4.6MB]
//   - LDS-read/CU = 2.3MB (~7.7us); MFMA/SIMD = 18.6us -> MFMA-bound.
//   - per step: 64 MFMA (~1240 SIMD-cyc) covers 8 B-loads + 16 ds_reads.
//  Registers: acc 8x4 f32x4 = 128 + B0[8]+B1[8] = 64 + af 16 + addr ~ 225
//  under (256,2)=256. Stage transient (17x2 float4) is pre-acc.
//  A-LDS: 4 input rows h0-1..h0+2, R12 geometry extended: [S=2][pr=4]
//  [wp=66][cs=8] chunks (sec stride 2112, row 528, line 128B), swizzle
//  (kk*4+q)^(wp&7) -> same per-lane algebra, conflict-free (R16-measured 0).
//  67584 B LDS, 2 blocks/CU = 135KB < 160KB. Single barrier.
// Epilogue: +bias, relu, store x bf16, atomic-accumulate s0.
// ---------------------------------------------------------------------------
__launch_bounds__(256, 2)
__global__ void k_conv(const float* __restrict__ in, const u16* __restrict__ BF,
                       const float* __restrict__ bias,
                       u16* __restrict__ X, float* __restrict__ s0) {
    __shared__ u16 ldsA[33792];                   // 4224 chunks x 16B = 67584 B
    const int t = threadIdx.x;
    const int lane = t & 63, wid = t >> 6;        // 4 waves = 4 n-groups
    const int q = lane >> 4, l15 = lane & 15;
    const int bb = blockIdx.x >> 5;               // batch
    const int h0 = (blockIdx.x & 31) << 1;        // first of 2 output rows
    const int wn0 = wid << 6;

    // full-K stage: 4224 slots = 2 sec x (4 pr x 66 wp x 8 cs), 256 thr,
    // 17 iters (last partial: 128). gc = S*8 + (cs^(wp&7)). Two-phase:
    // issue all 34 dwordx4 loads, then cvt+ds_write. Branchless borders.
#define STAGE_ALL() { \
    float4 fa[17], fb[17]; float zf[17]; \
    _Pragma("unroll") for (int i = 0; i < 17; ++i) { \
        int slot = i * 256 + t; \
        int ok = (i < 16) | (t < 128); \
        int S = slot / 2112; int r2 = slot - S * 2112; \
        int pr = r2 / 528; int rem = r2 - pr * 528; \
        int wp = rem >> 3, cs = rem & 7; \
        int gc = S * 8 + (cs ^ (wp & 7)); \
        int y = h0 + pr - 1, x = wp - 1; \
        int inb = ok & ((((unsigned)y < 64u) & ((unsigned)x < 64u)) ? 1 : 0); \
        int ys = inb ? y : 0, xs = inb ? x : 0; \
        const float4* s4 = (const float4*)(in + \
            (((bb * 64 + ys) * 64 + xs) * 128 + gc * 8)); \
        fa[i] = s4[0]; fb[i] = s4[1]; \
        zf[i] = inb ? 1.f : 0.f; \
    } \
    _Pragma("unroll") for (int i = 0; i < 17; ++i) { \
        if (i < 16 || t < 128) { \
            int slot = i * 256 + t; \
            u16 ov[8]; \
            ov[0]=f2b(fa[i].x*zf[i]); ov[1]=f2b(fa[i].y*zf[i]); \
            ov[2]=f2b(fa[i].z*zf[i]); ov[3]=f2b(fa[i].w*zf[i]); \
            ov[4]=f2b(fb[i].x*zf[i]); ov[5]=f2b(fb[i].y*zf[i]); \
            ov[6]=f2b(fb[i].z*zf[i]); ov[7]=f2b(fb[i].w*zf[i]); \
            uint4 wv; __builtin_memcpy(&wv, ov, 16); \
            *(uint4*)((char*)ldsA + slot * 16) = wv; \
        } \
    } }

    // load one 8-fragment B group: tap P, section S2 (k-groups S2*2, S2*2+1)
#define LOADB8(B, P, S2) { \
    _Pragma("unroll") for (int kk = 0; kk < 2; ++kk) \
    _Pragma("unroll") for (int ni = 0; ni < 4; ++ni) \
        B[kk * 4 + ni] = *(const bf16x8*)(BFl + (P) * 32768 + \
                                          ((S2) * 2 + kk) * 8192 + ni * 128); }

    // one 64-MFMA compute step for (DH, DW, section S2) using B group B.
    // mi: (mi>>2) = image row r (pr = r + DH), (mi&3) = 16-col w-block.
#define COMP8(B, DH, DW, S2) { \
    _Pragma("unroll") for (int kk = 0; kk < 2; ++kk) { \
        bf16x8 af[8]; \
        _Pragma("unroll") for (int mi = 0; mi < 8; ++mi) { \
            int wp = (mi & 3) * 16 + l15 + (DW); \
            int pr = (mi >> 2) + (DH); \
            int swz = (kk * 4 + q) ^ (wp & 7); \
            af[mi] = *(const bf16x8*)((const char*)ldsA + \
                (((S2) * 2112 + pr * 528 + wp * 8 + swz) << 4)); \
        } \
        _Pragma("unroll") for (int mi = 0; mi < 8; ++mi) \
        _Pragma("unroll") for (int ni = 0; ni < 4; ++ni) \
            acc[mi][ni] = __builtin_amdgcn_mfma_f32_16x16x32_bf16( \
                af[mi], B[kk * 4 + ni], acc[mi][ni], 0, 0, 0); } }

    const u16* BFl = BF + (q * 2048 + (wn0 + l15) * 8);

    STAGE_ALL();

    f32x4 zero = {0.f, 0.f, 0.f, 0.f};
    f32x4 acc[8][4];
    #pragma unroll
    for (int mi = 0; mi < 8; ++mi)
        #pragma unroll
        for (int ni = 0; ni < 4; ++ni) acc[mi][ni] = zero;

    bf16x8 B0[8], B1[8];
    LOADB8(B0, 0, 0);                             // in flight across barrier
    LOADB8(B1, 0, 1);
    __syncthreads();

    // 18-step barrier-free ping-pong, one-behind pairing. P = DH*3+DW.
    COMP8(B0, 0, 0, 0);
    LOADB8(B0, 1, 0); COMP8(B1, 0, 0, 1);
    LOADB8(B1, 1, 1); COMP8(B0, 0, 1, 0);
    LOADB8(B0, 2, 0); COMP8(B1, 0, 1, 1);
    LOADB8(B1, 2, 1); COMP8(B0, 0, 2, 0);
    LOADB8(B0, 3, 0); COMP8(B1, 0, 2, 1);
    LOADB8(B1, 3, 1); COMP8(B0, 1, 0, 0);
    LOADB8(B0, 4, 0); COMP8(B1, 1, 0, 1);
    LOADB8(B1, 4, 1); COMP8(B0, 1, 1, 0);
    LOADB8(B0, 5, 0); COMP8(B1, 1, 1, 1);
    LOADB8(B1, 5, 1); COMP8(B0, 1, 2, 0);
    LOADB8(B0, 6, 0); COMP8(B1, 1, 2, 1);
    LOADB8(B1, 6, 1); COMP8(B0, 2, 0, 0);
    LOADB8(B0, 7, 0); COMP8(B1, 2, 0, 1);
    LOADB8(B1, 7, 1); COMP8(B0, 2, 1, 0);
    LOADB8(B0, 8, 0); COMP8(B1, 2, 1, 1);
    LOADB8(B1, 8, 1); COMP8(B0, 2, 2, 0);
                      COMP8(B1, 2, 2, 1);

    // epilogue: bias + relu, store bf16 x, column sums -> s0
    float bv[4];
    #pragma unroll
    for (int ni = 0; ni < 4; ++ni) bv[ni] = bias[wn0 + ni * 16 + l15];
    float colsum[4] = {0.f, 0.f, 0.f, 0.f};
    #pragma unroll
    for (int mi = 0; mi < 8; ++mi) {
        // output position: h = h0 + (mi>>2), w = (mi&3)*16 + q*4 + rr
        u16* xp0 = X + ((((bb << 12) + (h0 + (mi >> 2)) * 64 +
                          (mi & 3) * 16 + q * 4)) * 256) + wn0 + l15;
        #pragma unroll
        for (int rr = 0; rr < 4; ++rr) {
            u16* xp = xp0 + rr * 256;
            #pragma unroll
            for (int ni = 0; ni < 4; ++ni) {
                float v = acc[mi][ni][rr] + bv[ni];
                v = v > 0.f ? v : 0.f;
                xp[ni * 16] = f2b(v);
                colsum[ni] += v;
            }
        }
    }
    #pragma unroll
    for (int ni = 0; ni < 4; ++ni) {
        float c = colsum[ni];
        c += __shfl_xor(c, 16);
        c += __shfl_xor(c, 32);
        if (lane < 16) atomicAdd(&s0[bb * 256 + wn0 + ni * 16 + l15], c);
    }
#undef STAGE_ALL
#undef LOADB8
#undef COMP8
}

// ---------------------------------------------------------------------------
// routing pass v3 (unchanged, R9/R11-measured best): 64 positions/block,
// grid 64x16. vsum register-cached -> ONE dot per position. Stride-17 LDS,
// 8 outstanding X-loads, shfl n-reduce. b-logits bounded -> no max pass.
// ---------------------------------------------------------------------------
__launch_bounds__(256, 4)
__global__ void k_pass(const u16* __restrict__ X, const float* __restrict__ Sa,
                       const float* __restrict__ Sb, float* __restrict__ Sout,
                       int use2) {
    __shared__ float vs[272];                     // [cap*17 + d]
    __shared__ float red[4 * 272];                // [wave][c*17 + d]
    const int t = threadIdx.x, b = blockIdx.y, chunk = blockIdx.x;
    const int c = t & 15, nl = t >> 4;
    const int lane = t & 63, wid = t >> 6;
    {
        float sa = Sa[b * 256 + t];
        float ss = sa * sa;
        #pragma unroll
        for (int off = 1; off < 16; off <<= 1) ss += __shfl_xor(ss, off);
        ss = ss < 1e-12f ? 1e-12f : ss;
        float vv = sa / sqrtf(ss);
        if (use2) {
            float sb = Sb[b * 256 + t];
            float s2v = sb * sb;
            #pragma unroll
            for (int off = 1; off < 16; off <<= 1) s2v += __shfl_xor(s2v, off);
            s2v = s2v < 1e-12f ? 1e-12f : s2v;
            vv += sb / sqrtf(s2v);
        }
        vs[(t >> 4) * 17 + (t & 15)] = vv;
    }
    // prefetch all 4 positions (8 outstanding 16B loads) while v finishes
    const u16* xbase = X + ((b << 12) + chunk * 64 + nl) * 256 + c * 16;
    uint4 pa[8];
    #pragma unroll
    for (int r = 0; r < 4; ++r) {
        pa[2 * r]     = ((const uint4*)(xbase + r * 4096))[0];
        pa[2 * r + 1] = ((const uint4*)(xbase + r * 4096))[1];
    }
    __syncthreads();
    // register-cache this thread's vsum row (conflict-free: stride 17)
    float vr[16];
    #pragma unroll
    for (int d = 0; d < 16; ++d) vr[d] = vs[c * 17 + d];

    float acc[16];
    #pragma unroll
    for (int d = 0; d < 16; ++d) acc[d] = 0.f;

    #pragma unroll
    for (int r = 0; r < 4; ++r) {
        u32 us[8];
        __builtin_memcpy(us, &pa[2 * r], 32);
        float xf[16];
        #pragma unroll
        for (int j = 0; j < 8; ++j) { xf[2*j] = blo(us[j]); xf[2*j+1] = bhi(us[j]); }
        float bvv = 0.f;
        #pragma unroll
        for (int d = 0; d < 16; ++d) bvv += xf[d] * vr[d];
        float e = __expf(bvv);                    // |b| small: stable w/o max
        float sm = e;
        #pragma unroll
        for (int off = 1; off < 16; off <<= 1) sm += __shfl_xor(sm, off);
        float w = e / sm;
        #pragma unroll
        for (int d = 0; d < 16; ++d) acc[d] += w * xf[d];
    }
    // reduce the wave's 4 nl groups (lanes +-16, +-32) -> lanes 0..15
    #pragma unroll
    for (int d = 0; d < 16; ++d) {
        acc[d] += __shfl_xor(acc[d], 16);
        acc[d] += __shfl_xor(acc[d], 32);
    }
    if (lane < 16) {
        #pragma unroll
        for (int d = 0; d < 16; ++d) red[wid * 272 + lane * 17 + d] = acc[d];
    }
    __syncthreads();
    {
        int c2 = t >> 4, d2 = t & 15;
        float tot = red[c2 * 17 + d2]       + red[272 + c2 * 17 + d2]
                  + red[544 + c2 * 17 + d2] + red[816 + c2 * 17 + d2];
        atomicAdd(&Sout[b * 256 + t], tot);
    }
}

// ---------------------------------------------------------------------------
// final: v = l2_normalize(s3), broadcast to (B,64,64,256) fp32. (unchanged)
// ---------------------------------------------------------------------------
__launch_bounds__(256, 4)
__global__ void k_bcast(const float* __restrict__ S, float* __restrict__ Out) {
    __shared__ float vls[256];
    int t = threadIdx.x, bx = blockIdx.x, b = blockIdx.y;
    float s = S[b * 256 + t];
    float ss = s * s;
    #pragma unroll
    for (int off = 1; off < 16; off <<= 1) ss += __shfl_xor(ss, off);
    ss = ss < 1e-12f ? 1e-12f : ss;
    vls[t] = s / sqrtf(ss);
    __syncthreads();
    float4 myv = ((const float4*)vls)[t & 63];    // (j*256+t)&63 == t&63
    float4* o = (float4*)Out + (long)b * 262144 + bx * 4096;
    #pragma unroll
    for (int j = 0; j < 16; ++j) o[j * 256 + t] = myv;
}

// ---------------------------------------------------------------------------
extern "C" void kernel_launch(void* const* d_in, const int* in_sizes, int n_in,
                              void* d_out, int out_size, void* d_ws, size_t ws_size,
                              hipStream_t stream) {
    const float* in   = (const float*)d_in[0];   // (16,64,64,128)
    const float* wk   = (const float*)d_in[1];   // (3,3,128,256)
    const float* bias = (const float*)d_in[2];   // (256,)
    float* out = (float*)d_out;
    char* ws = (char*)d_ws;

    // workspace layout (bytes)
    const size_t OFF_BF  = 0;                    // 294912*2      =    589,824
    const size_t OFF_X   = 589824;               // 16*4096*256*2 = 33,554,432
    const size_t OFF_ST  = 34144256;             // s0,s2,s3      = 3*16,384
    const size_t NEEDED  = OFF_ST + 3 * 16384;
    if (ws_size < NEEDED) return;                // fail loudly (validation error)

    u16* BF  = (u16*)(ws + OFF_BF);
    u16* X   = (u16*)(ws + OFF_X);
    float* s0 = (float*)(ws + OFF_ST);
    float* s2 = s0 + 4096;
    float* s3 = s2 + 4096;

    k_prep <<<1200, 256, 0, stream>>>(wk, BF, s0);
    k_conv <<<512, 256, 0, stream>>>(in, BF, bias, X, s0);
    k_pass <<<dim3(64, 16), 256, 0, stream>>>(X, s0, s0, s2, 0);
    k_pass <<<dim3(64, 16), 256, 0, stream>>>(X, s0, s2, s3, 1);
    k_bcast<<<dim3(64, 16), 256, 0, stream>>>(s3, out);
}

// Round 6
// 161.179 us; speedup vs baseline: 1.1695x; 1.1695x over previous
//
#include <hip/hip_runtime.h>
#include <hip/hip_bf16.h>

typedef unsigned short u16;
typedef unsigned int   u32;

typedef __bf16 bf16x8 __attribute__((ext_vector_type(8)));
typedef float  f32x4  __attribute__((ext_vector_type(4)));

__device__ __forceinline__ u16 f2b(float f) {
    __hip_bfloat16 h = __float2bfloat16(f);
    u16 u; __builtin_memcpy(&u, &h, 2); return u;
}
__device__ __forceinline__ float blo(u32 u) { return __uint_as_float(u << 16); }
__device__ __forceinline__ float bhi(u32 u) { return __uint_as_float(u & 0xffff0000u); }

// ---------------------------------------------------------------------------
// prep (unchanged):
//  section B (blocks [0,1152)):    weights -> MFMA B-fragment order
//       BF[(((p*4+g)*4+q)*256 + n)*8 + j] = bf16(w[(p*128+g*32+q*8+j)*256+n])
//  section C (blocks [1152,1200)): zero s0,s2,s3 (12288 floats)
// ---------------------------------------------------------------------------
__global__ void k_prep(const float* __restrict__ wk,
                       u16* __restrict__ BF, float* __restrict__ stats) {
    int bx = blockIdx.x, tid = threadIdx.x;
    if (bx < 1152) {
        int t = bx * 256 + tid;                   // 294912 total, exact
        int j  = t & 7;
        int n  = (t >> 3) & 255;
        int q  = (t >> 11) & 3;
        int kk = (t >> 13) & 3;
        int p  = t >> 15;
        BF[t] = f2b(wk[(p * 128 + kk * 32 + q * 8 + j) * 256 + n]);
    } else {
        stats[(bx - 1152) * 256 + tid] = 0.f;     // 12288 floats
    }
}

// ---------------------------------------------------------------------------
// conv: implicit GEMM. R18 = R17 algebra (correct, passed) with register
// pressure engineered out.
// Post-mortem chain:
//  R13: allocator squeeze -> spill. R15: 4-frag ping-pong + LDS conflicts.
//  R16: conflicts fixed, occupancy 36%, still 67us -> occupancy not the
//       limiter; B-VMEM/CU tracks duration.
//  R17: M=128/block (B-VMEM/CU 4x down) but STAGE_ALL held 17x36B of
//       transient regs -> spill (WRITE 34.8->208MB), k_conv 88us.
// R18 fixes ONLY the pressure:
//  - Rolling depth-4 stage: issue slot i, write slot i-4; transient ~50
//    regs (was ~140). Fully unrolled, ring idx i&3 compile-time.
//  - COMP8 A-fragments in af[4] groups (g = image row), transient 16 regs.
//  - Steady K-loop demand: acc 128 + B 64 + af 16 + addr ~25 = 233 < 256
//    @ (256,2). Guard metric: WRITE_SIZE must stay ~34.8MB (no scratch).
// Geometry (R17): block = 2 image rows, M=128, N=256, K=1152; 4 waves,
//  wave tile 128x64 (mi>>2 = row, mi&3 = w-block). Grid 512 = 2 blocks/CU,
//  whole grid resident, B read once per block -> B-VMEM/CU = 1.15MB (~8us).
//  LDS [S=2][pr=4][wp=66][cs=8] chunks, swizzle (kk*4+q)^(wp&7) —
//  R12/R16-measured conflict-free. 67584B, 2 blocks/CU = 135KB. 1 barrier.
// ---------------------------------------------------------------------------
__launch_bounds__(256, 2)
__global__ void k_conv(const float* __restrict__ in, const u16* __restrict__ BF,
                       const float* __restrict__ bias,
                       u16* __restrict__ X, float* __restrict__ s0) {
    __shared__ u16 ldsA[33792];                   // 4224 chunks x 16B = 67584 B
    const int t = threadIdx.x;
    const int lane = t & 63, wid = t >> 6;        // 4 waves = 4 n-groups
    const int q = lane >> 4, l15 = lane & 15;
    const int bb = blockIdx.x >> 5;               // batch
    const int h0 = (blockIdx.x & 31) << 1;        // first of 2 output rows
    const int wn0 = wid << 6;

    // one slot's global load (predicated via clamped address + zero factor)
#define SLOT_CALC(I, FA, FB, ZF) { \
    int slot = (I) * 256 + t; \
    int ok = ((I) < 16) | (t < 128); \
    int S = slot / 2112; int r2 = slot - S * 2112; \
    int pr = r2 / 528; int rem = r2 - pr * 528; \
    int wp = rem >> 3, cs = rem & 7; \
    int gc = S * 8 + (cs ^ (wp & 7)); \
    int y = h0 + pr - 1, x = wp - 1; \
    int inb = ok & ((((unsigned)y < 64u) & ((unsigned)x < 64u)) ? 1 : 0); \
    int ys = inb ? y : 0, xs = inb ? x : 0; \
    const float4* s4 = (const float4*)(in + \
        (((bb * 64 + ys) * 64 + xs) * 128 + gc * 8)); \
    FA = s4[0]; FB = s4[1]; ZF = inb ? 1.f : 0.f; }

    // one slot's cvt + LDS write
#define SLOT_WRITE(I, FA, FB, ZF) { \
    if ((I) < 16 || t < 128) { \
        int slot = (I) * 256 + t; \
        u16 ov[8]; \
        ov[0]=f2b(FA.x*ZF); ov[1]=f2b(FA.y*ZF); \
        ov[2]=f2b(FA.z*ZF); ov[3]=f2b(FA.w*ZF); \
        ov[4]=f2b(FB.x*ZF); ov[5]=f2b(FB.y*ZF); \
        ov[6]=f2b(FB.z*ZF); ov[7]=f2b(FB.w*ZF); \
        uint4 wv; __builtin_memcpy(&wv, ov, 16); \
        *(uint4*)((char*)ldsA + slot * 16) = wv; \
    } }

    // load one 8-fragment B group: tap P, section S2 (k-groups S2*2, S2*2+1)
#define LOADB8(B, P, S2) { \
    _Pragma("unroll") for (int kk = 0; kk < 2; ++kk) \
    _Pragma("unroll") for (int ni = 0; ni < 4; ++ni) \
        B[kk * 4 + ni] = *(const bf16x8*)(BFl + (P) * 32768 + \
                                          ((S2) * 2 + kk) * 8192 + ni * 128); }

    // one 64-MFMA compute step for (DH, DW, section S2) using B group B.
    // g = image row (pr = g + DH); m4 = 16-col w-block. af[4] transient.
#define COMP8(B, DH, DW, S2) { \
    _Pragma("unroll") for (int kk = 0; kk < 2; ++kk) { \
        _Pragma("unroll") for (int g = 0; g < 2; ++g) { \
            bf16x8 af[4]; \
            _Pragma("unroll") for (int m4 = 0; m4 < 4; ++m4) { \
                int wp = m4 * 16 + l15 + (DW); \
                int pr = g + (DH); \
                int swz = (kk * 4 + q) ^ (wp & 7); \
                af[m4] = *(const bf16x8*)((const char*)ldsA + \
                    (((S2) * 2112 + pr * 528 + wp * 8 + swz) << 4)); \
            } \
            _Pragma("unroll") for (int m4 = 0; m4 < 4; ++m4) \
            _Pragma("unroll") for (int ni = 0; ni < 4; ++ni) \
                acc[g * 4 + m4][ni] = __builtin_amdgcn_mfma_f32_16x16x32_bf16( \
                    af[m4], B[kk * 4 + ni], acc[g * 4 + m4][ni], 0, 0, 0); \
        } } }

    const u16* BFl = BF + (q * 2048 + (wn0 + l15) * 8);

    // rolling depth-4 stage: 17 slot-groups (last partial), write trails by 4
    {
        float4 fa[4], fb[4]; float zf[4];
        #pragma unroll
        for (int i = 0; i < 21; ++i) {
            if (i >= 4) { SLOT_WRITE(i - 4, fa[(i - 4) & 3], fb[(i - 4) & 3],
                                     zf[(i - 4) & 3]); }
            if (i < 17) { SLOT_CALC(i, fa[i & 3], fb[i & 3], zf[i & 3]); }
        }
    }

    f32x4 zero = {0.f, 0.f, 0.f, 0.f};
    f32x4 acc[8][4];
    #pragma unroll
    for (int mi = 0; mi < 8; ++mi)
        #pragma unroll
        for (int ni = 0; ni < 4; ++ni) acc[mi][ni] = zero;

    bf16x8 B0[8], B1[8];
    LOADB8(B0, 0, 0);                             // in flight across barrier
    LOADB8(B1, 0, 1);
    __syncthreads();

    // 18-step barrier-free ping-pong, one-behind pairing. P = DH*3+DW.
    COMP8(B0, 0, 0, 0);
    LOADB8(B0, 1, 0); COMP8(B1, 0, 0, 1);
    LOADB8(B1, 1, 1); COMP8(B0, 0, 1, 0);
    LOADB8(B0, 2, 0); COMP8(B1, 0, 1, 1);
    LOADB8(B1, 2, 1); COMP8(B0, 0, 2, 0);
    LOADB8(B0, 3, 0); COMP8(B1, 0, 2, 1);
    LOADB8(B1, 3, 1); COMP8(B0, 1, 0, 0);
    LOADB8(B0, 4, 0); COMP8(B1, 1, 0, 1);
    LOADB8(B1, 4, 1); COMP8(B0, 1, 1, 0);
    LOADB8(B0, 5, 0); COMP8(B1, 1, 1, 1);
    LOADB8(B1, 5, 1); COMP8(B0, 1, 2, 0);
    LOADB8(B0, 6, 0); COMP8(B1, 1, 2, 1);
    LOADB8(B1, 6, 1); COMP8(B0, 2, 0, 0);
    LOADB8(B0, 7, 0); COMP8(B1, 2, 0, 1);
    LOADB8(B1, 7, 1); COMP8(B0, 2, 1, 0);
    LOADB8(B0, 8, 0); COMP8(B1, 2, 1, 1);
    LOADB8(B1, 8, 1); COMP8(B0, 2, 2, 0);
                      COMP8(B1, 2, 2, 1);

    // epilogue: bias + relu, store bf16 x, column sums -> s0
    float bv[4];
    #pragma unroll
    for (int ni = 0; ni < 4; ++ni) bv[ni] = bias[wn0 + ni * 16 + l15];
    float colsum[4] = {0.f, 0.f, 0.f, 0.f};
    #pragma unroll
    for (int mi = 0; mi < 8; ++mi) {
        // output position: h = h0 + (mi>>2), w = (mi&3)*16 + q*4 + rr
        u16* xp0 = X + ((((bb << 12) + (h0 + (mi >> 2)) * 64 +
                          (mi & 3) * 16 + q * 4)) * 256) + wn0 + l15;
        #pragma unroll
        for (int rr = 0; rr < 4; ++rr) {
            u16* xp = xp0 + rr * 256;
            #pragma unroll
            for (int ni = 0; ni < 4; ++ni) {
                float v = acc[mi][ni][rr] + bv[ni];
                v = v > 0.f ? v : 0.f;
                xp[ni * 16] = f2b(v);
                colsum[ni] += v;
            }
        }
    }
    #pragma unroll
    for (int ni = 0; ni < 4; ++ni) {
        float c = colsum[ni];
        c += __shfl_xor(c, 16);
        c += __shfl_xor(c, 32);
        if (lane < 16) atomicAdd(&s0[bb * 256 + wn0 + ni * 16 + l15], c);
    }
#undef SLOT_CALC
#undef SLOT_WRITE
#undef LOADB8
#undef COMP8
}

// ---------------------------------------------------------------------------
// routing pass v3 (unchanged, R9/R11-measured best): 64 positions/block,
// grid 64x16. vsum register-cached -> ONE dot per position. Stride-17 LDS,
// 8 outstanding X-loads, shfl n-reduce. b-logits bounded -> no max pass.
// ---------------------------------------------------------------------------
__launch_bounds__(256, 4)
__global__ void k_pass(const u16* __restrict__ X, const float* __restrict__ Sa,
                       const float* __restrict__ Sb, float* __restrict__ Sout,
                       int use2) {
    __shared__ float vs[272];                     // [cap*17 + d]
    __shared__ float red[4 * 272];                // [wave][c*17 + d]
    const int t = threadIdx.x, b = blockIdx.y, chunk = blockIdx.x;
    const int c = t & 15, nl = t >> 4;
    const int lane = t & 63, wid = t >> 6;
    {
        float sa = Sa[b * 256 + t];
        float ss = sa * sa;
        #pragma unroll
        for (int off = 1; off < 16; off <<= 1) ss += __shfl_xor(ss, off);
        ss = ss < 1e-12f ? 1e-12f : ss;
        float vv = sa / sqrtf(ss);
        if (use2) {
            float sb = Sb[b * 256 + t];
            float s2v = sb * sb;
            #pragma unroll
            for (int off = 1; off < 16; off <<= 1) s2v += __shfl_xor(s2v, off);
            s2v = s2v < 1e-12f ? 1e-12f : s2v;
            vv += sb / sqrtf(s2v);
        }
        vs[(t >> 4) * 17 + (t & 15)] = vv;
    }
    // prefetch all 4 positions (8 outstanding 16B loads) while v finishes
    const u16* xbase = X + ((b << 12) + chunk * 64 + nl) * 256 + c * 16;
    uint4 pa[8];
    #pragma unroll
    for (int r = 0; r < 4; ++r) {
        pa[2 * r]     = ((const uint4*)(xbase + r * 4096))[0];
        pa[2 * r + 1] = ((const uint4*)(xbase + r * 4096))[1];
    }
    __syncthreads();
    // register-cache this thread's vsum row (conflict-free: stride 17)
    float vr[16];
    #pragma unroll
    for (int d = 0; d < 16; ++d) vr[d] = vs[c * 17 + d];

    float acc[16];
    #pragma unroll
    for (int d = 0; d < 16; ++d) acc[d] = 0.f;

    #pragma unroll
    for (int r = 0; r < 4; ++r) {
        u32 us[8];
        __builtin_memcpy(us, &pa[2 * r], 32);
        float xf[16];
        #pragma unroll
        for (int j = 0; j < 8; ++j) { xf[2*j] = blo(us[j]); xf[2*j+1] = bhi(us[j]); }
        float bvv = 0.f;
        #pragma unroll
        for (int d = 0; d < 16; ++d) bvv += xf[d] * vr[d];
        float e = __expf(bvv);                    // |b| small: stable w/o max
        float sm = e;
        #pragma unroll
        for (int off = 1; off < 16; off <<= 1) sm += __shfl_xor(sm, off);
        float w = e / sm;
        #pragma unroll
        for (int d = 0; d < 16; ++d) acc[d] += w * xf[d];
    }
    // reduce the wave's 4 nl groups (lanes +-16, +-32) -> lanes 0..15
    #pragma unroll
    for (int d = 0; d < 16; ++d) {
        acc[d] += __shfl_xor(acc[d], 16);
        acc[d] += __shfl_xor(acc[d], 32);
    }
    if (lane < 16) {
        #pragma unroll
        for (int d = 0; d < 16; ++d) red[wid * 272 + lane * 17 + d] = acc[d];
    }
    __syncthreads();
    {
        int c2 = t >> 4, d2 = t & 15;
        float tot = red[c2 * 17 + d2]       + red[272 + c2 * 17 + d2]
                  + red[544 + c2 * 17 + d2] + red[816 + c2 * 17 + d2];
        atomicAdd(&Sout[b * 256 + t], tot);
    }
}

// ---------------------------------------------------------------------------
// final: v = l2_normalize(s3), broadcast to (B,64,64,256) fp32. (unchanged)
// ---------------------------------------------------------------------------
__launch_bounds__(256, 4)
__global__ void k_bcast(const float* __restrict__ S, float* __restrict__ Out) {
    __shared__ float vls[256];
    int t = threadIdx.x, bx = blockIdx.x, b = blockIdx.y;
    float s = S[b * 256 + t];
    float ss = s * s;
    #pragma unroll
    for (int off = 1; off < 16; off <<= 1) ss += __shfl_xor(ss, off);
    ss = ss < 1e-12f ? 1e-12f : ss;
    vls[t] = s / sqrtf(ss);
    __syncthreads();
    float4 myv = ((const float4*)vls)[t & 63];    // (j*256+t)&63 == t&63
    float4* o = (float4*)Out + (long)b * 262144 + bx * 4096;
    #pragma unroll
    for (int j = 0; j < 16; ++j) o[j * 256 + t] = myv;
}

// ---------------------------------------------------------------------------
extern "C" void kernel_launch(void* const* d_in, const int* in_sizes, int n_in,
                              void* d_out, int out_size, void* d_ws, size_t ws_size,
                              hipStream_t stream) {
    const float* in   = (const float*)d_in[0];   // (16,64,64,128)
    const float* wk   = (const float*)d_in[1];   // (3,3,128,256)
    const float* bias = (const float*)d_in[2];   // (256,)
    float* out = (float*)d_out;
    char* ws = (char*)d_ws;

    // workspace layout (bytes)
    const size_t OFF_BF  = 0;                    // 294912*2      =    589,824
    const size_t OFF_X   = 589824;               // 16*4096*256*2 = 33,554,432
    const size_t OFF_ST  = 34144256;             // s0,s2,s3      = 3*16,384
    const size_t NEEDED  = OFF_ST + 3 * 16384;
    if (ws_size < NEEDED) return;                // fail loudly (validation error)

    u16* BF  = (u16*)(ws + OFF_BF);
    u16* X   = (u16*)(ws + OFF_X);
    float* s0 = (float*)(ws + OFF_ST);
    float* s2 = s0 + 4096;
    float* s3 = s2 + 4096;

    k_prep <<<1200, 256, 0, stream>>>(wk, BF, s0);
    k_conv <<<512, 256, 0, stream>>>(in, BF, bias, X, s0);
    k_pass <<<dim3(64, 16), 256, 0, stream>>>(X, s0, s0, s2, 0);
    k_pass <<<dim3(64, 16), 256, 0, stream>>>(X, s0, s2, s3, 1);
    k_bcast<<<dim3(64, 16), 256, 0, stream>>>(s3, out);
}